// Round 1
// baseline (586.108 us; speedup 1.0000x reference)
//
#include <hip/hip_runtime.h>
#include <math.h>

#define N_NODES 100000
#define N_EDGES 1600000
#define IN_DIM 128
#define OUT_DIM 64

// K1: Wh = h @ W.T  (per block: 4 nodes x 64 dims), plus per-node scalars
// s1[n] = Wh[n]·a_w[0:64], s2[n] = Wh[n]·a_w[64:128] via wave shuffle-reduce
// (each 64-lane wave owns exactly one node; lane index == output dim).
__global__ __launch_bounds__(256) void k_wh(const float* __restrict__ h,
                                            const float* __restrict__ W,
                                            const float* __restrict__ a_w,
                                            float* __restrict__ Wh,
                                            float* __restrict__ s1,
                                            float* __restrict__ s2) {
    // pad to 129 floats: LDS read Ws[d][k] across lanes d=0..63 -> bank (d+k)%32,
    // 2 lanes/bank = free (m136)
    __shared__ float Ws[OUT_DIM][IN_DIM + 1];   // ~33 KB
    __shared__ float hs[4][IN_DIM];             // 2 KB
    const int tid = threadIdx.x;
    for (int i = tid; i < OUT_DIM * IN_DIM; i += 256)
        Ws[i >> 7][i & 127] = W[i];
    const int node0 = blockIdx.x * 4;
    for (int i = tid; i < 4 * IN_DIM; i += 256) {
        int n = node0 + (i >> 7);
        hs[i >> 7][i & 127] = (n < N_NODES) ? h[(size_t)n * IN_DIM + (i & 127)] : 0.f;
    }
    __syncthreads();
    const int local = tid >> 6;   // which of the 4 nodes
    const int d = tid & 63;       // output dim == lane
    const int n = node0 + local;
    float acc = 0.f;
    #pragma unroll 8
    for (int k = 0; k < IN_DIM; ++k)
        acc = fmaf(hs[local][k], Ws[d][k], acc);
    // wave-level reduction over 64 lanes for the two attention scalars
    float v1 = acc * a_w[d];
    float v2 = acc * a_w[64 + d];
    #pragma unroll
    for (int off = 32; off > 0; off >>= 1) {
        v1 += __shfl_xor(v1, off, 64);
        v2 += __shfl_xor(v2, off, 64);
    }
    if (n < N_NODES) {
        Wh[(size_t)n * OUT_DIM + d] = acc;
        if (d == 0) { s1[n] = v1; s2[n] = v2; }
    }
}

// K2: per-edge attention logit -> exp -> segment-sum denominator.
// Global-max subtraction is skipped: it cancels exactly in alpha_norm
// (both numerator and per-dst denominator scale by exp(-M); 1e-9 eps is
// ~1e-8 relative vs the sums). alpha <= ~6 so expf is safe in f32.
__global__ __launch_bounds__(256) void k_edge_alpha(const int* __restrict__ ei,
                                                    const float* __restrict__ s1,
                                                    const float* __restrict__ s2,
                                                    float* __restrict__ alpha_exp,
                                                    float* __restrict__ alpha_sum) {
    int e = blockIdx.x * 256 + threadIdx.x;
    if (e >= N_EDGES) return;
    int src = ei[e];
    int dst = ei[N_EDGES + e];
    float a = s1[src] + s2[dst];
    a = (a > 0.f) ? a : 0.2f * a;           // leaky_relu(0.2)
    float ae = expf(a);
    alpha_exp[e] = ae;
    atomicAdd(&alpha_sum[dst], ae);
}

// K3: one 64-lane group per edge: alpha_norm + weighted scatter-add of Wh[src].
__global__ __launch_bounds__(256) void k_aggregate(const int* __restrict__ ei,
                                                   const float* __restrict__ Wh,
                                                   const float* __restrict__ alpha_exp,
                                                   const float* __restrict__ alpha_sum,
                                                   float* __restrict__ out_acc,
                                                   float* __restrict__ alpha_norm) {
    int gid = blockIdx.x * 256 + threadIdx.x;   // max 102.4M < 2^31
    int e = gid >> 6;
    int d = gid & 63;
    if (e >= N_EDGES) return;
    int src = ei[e];
    int dst = ei[N_EDGES + e];
    float an = alpha_exp[e] / (alpha_sum[dst] + 1e-9f);
    atomicAdd(&out_acc[(size_t)dst * OUT_DIM + d], an * Wh[(size_t)src * OUT_DIM + d]);
    if (d == 0) alpha_norm[e] = an;
}

// K4: ELU in place on the aggregated output.
__global__ __launch_bounds__(256) void k_elu(float* __restrict__ out) {
    int i = blockIdx.x * 256 + threadIdx.x;
    if (i < N_NODES * OUT_DIM) {
        float x = out[i];
        out[i] = (x > 0.f) ? x : expf(x) - 1.f;
    }
}

extern "C" void kernel_launch(void* const* d_in, const int* in_sizes, int n_in,
                              void* d_out, int out_size, void* d_ws, size_t ws_size,
                              hipStream_t stream) {
    const float* h   = (const float*)d_in[0];
    const float* W   = (const float*)d_in[1];
    const float* a_w = (const float*)d_in[2];
    const int*   ei  = (const int*)d_in[3];    // [2, E]: row0=src, row1=dst

    float* out        = (float*)d_out;                       // [N, 64] elu(out)
    float* alpha_norm = out + (size_t)N_NODES * OUT_DIM;     // [E]

    // workspace layout (33.2 MB total)
    char* ws = (char*)d_ws;
    float* Wh        = (float*)ws;  ws += (size_t)N_NODES * OUT_DIM * 4;
    float* s1        = (float*)ws;  ws += (size_t)N_NODES * 4;
    float* s2        = (float*)ws;  ws += (size_t)N_NODES * 4;
    float* alpha_exp = (float*)ws;  ws += (size_t)N_EDGES * 4;
    float* alpha_sum = (float*)ws;  ws += (size_t)N_NODES * 4;

    // accumulators must be zeroed every call (harness does not re-poison)
    hipMemsetAsync(alpha_sum, 0, (size_t)N_NODES * 4, stream);
    hipMemsetAsync(out, 0, (size_t)N_NODES * OUT_DIM * 4, stream);

    k_wh<<<(N_NODES + 3) / 4, 256, 0, stream>>>(h, W, a_w, Wh, s1, s2);
    k_edge_alpha<<<(N_EDGES + 255) / 256, 256, 0, stream>>>(ei, s1, s2, alpha_exp, alpha_sum);
    k_aggregate<<<(N_EDGES * 64) / 256, 256, 0, stream>>>(ei, Wh, alpha_exp, alpha_sum,
                                                          out, alpha_norm);
    k_elu<<<((N_NODES * OUT_DIM) + 255) / 256, 256, 0, stream>>>(out);
}